// Round 1
// baseline (320.581 us; speedup 1.0000x reference)
//
#include <hip/hip_runtime.h>
#include <math.h>

// S4D forward (conv mode) via chunked linear recurrence.
// y[b,l,d] = D[d]*x[b,l,d] + sum_n CB[d,n] * h_n[l],  h_n[l] = a_n h_n[l-1] + x[l]
// a = exp(dt*A), CB = C * expm1(dt*A)/A * B, A_n = -0.5*(n+1)
//
// P0: coefficients (a, cb, a^T) into ws tables, layout [n][d] (d fastest, coalesced).
// P1: per (b,d,chunk): local recurrence from zero state -> y_local + end state u.
// P2: scan over chunks: s[c+1] = a^T s[c] + u[c]  (in-place, u becomes s_start).
// P3: y += sum_n cb_n a_n^{t+1} s_start[c,n].

namespace {
constexpr int kBatch = 8;
constexpr int kLen   = 2048;
constexpr int kD     = 1024;
constexpr int kN     = 64;   // states
constexpr int kT     = 64;   // chunk length
constexpr int kC     = kLen / kT;  // 32 chunks

constexpr long kUElems = (long)kBatch * kC * kN * kD;   // 16,777,216 floats
constexpr long kAOff   = kUElems;                        // a[n][d]
constexpr long kCbOff  = kAOff + (long)kN * kD;          // cb[n][d]
constexpr long kAtOff  = kCbOff + (long)kN * kD;         // a^T[n][d]
// total ws: (16777216 + 3*65536)*4 B = 67,895,296 B (~64.8 MiB)
}  // namespace

__global__ void s4d_coef_kernel(const float* __restrict__ log_dt,
                                const float* __restrict__ Bm,
                                const float* __restrict__ Cm,
                                float* __restrict__ ws) {
  int tid = blockIdx.x * blockDim.x + threadIdx.x;  // 65536 threads
  int d = tid & (kD - 1);
  int n = tid >> 10;
  float dt  = expf(log_dt[d]);
  float An  = -0.5f * (float)(n + 1);
  float dtA = dt * An;
  float a   = expf(dtA);
  float bbar = (expm1f(dtA) / An) * Bm[d * kN + n];
  float cb   = Cm[d * kN + n] * bbar;
  float aT   = expf(dtA * (float)kT);  // a^64
  ws[kAOff  + (long)n * kD + d] = a;
  ws[kCbOff + (long)n * kD + d] = cb;
  ws[kAtOff + (long)n * kD + d] = aT;
}

__global__ __launch_bounds__(256, 2) void s4d_chunk_kernel(
    const float* __restrict__ x, const float* __restrict__ Dv,
    float* __restrict__ y, float* __restrict__ ws) {
  int tid = blockIdx.x * blockDim.x + threadIdx.x;  // 262144 threads
  int d  = tid & (kD - 1);   // lanes -> consecutive d: coalesced
  int bc = tid >> 10;
  int b  = bc >> 5;          // / kC
  int c  = bc & (kC - 1);

  float a[kN], cb[kN], h[kN];
  {
    const float* ap  = ws + kAOff + d;
    const float* cbp = ws + kCbOff + d;
#pragma unroll
    for (int n = 0; n < kN; ++n) {
      a[n]  = ap[(long)n * kD];
      cb[n] = cbp[(long)n * kD];
      h[n]  = 0.f;
    }
  }
  float Dd = Dv[d];
  const float* xp = x + ((long)b * kLen + (long)c * kT) * kD + d;
  float*       yp = y + ((long)b * kLen + (long)c * kT) * kD + d;

  float xv = xp[0];
#pragma unroll 1
  for (int t = 0; t < kT; ++t) {
    int tn = (t + 1 < kT) ? (t + 1) : (kT - 1);
    float xnext = xp[(long)tn * kD];  // prefetch (redundant but in-bounds at last iter)
#pragma unroll
    for (int n = 0; n < kN; ++n) h[n] = fmaf(h[n], a[n], xv);
    float acc[8] = {0.f, 0.f, 0.f, 0.f, 0.f, 0.f, 0.f, 0.f};
#pragma unroll
    for (int n = 0; n < kN; ++n) acc[n & 7] = fmaf(cb[n], h[n], acc[n & 7]);
    float s01 = acc[0] + acc[1], s23 = acc[2] + acc[3];
    float s45 = acc[4] + acc[5], s67 = acc[6] + acc[7];
    float sum = (s01 + s23) + (s45 + s67);
    yp[(long)t * kD] = fmaf(Dd, xv, sum);
    xv = xnext;
  }
  // store chunk-local end state u[b][c][n][d]
  float* up = ws + ((long)(b * kC + c) * kN) * kD + d;
#pragma unroll
  for (int n = 0; n < kN; ++n) up[(long)n * kD] = h[n];
}

__global__ void s4d_scan_kernel(float* __restrict__ ws) {
  int tid = blockIdx.x * blockDim.x + threadIdx.x;  // 524288 threads
  int d  = tid & (kD - 1);
  int bn = tid >> 10;
  int n  = bn & (kN - 1);
  int b  = bn >> 6;
  float aT = ws[kAtOff + (long)n * kD + d];
  float* up = ws + ((long)b * kC * kN + n) * kD + d;
  const long cstride = (long)kN * kD;
  float s = 0.f;
#pragma unroll 1
  for (int c = 0; c < kC; ++c) {
    float u = up[(long)c * cstride];
    up[(long)c * cstride] = s;  // in place: u[c] -> s_start[c]
    s = fmaf(aT, s, u);
  }
}

__global__ __launch_bounds__(256, 2) void s4d_corr_kernel(
    float* __restrict__ y, float* __restrict__ ws) {
  int tid = blockIdx.x * blockDim.x + threadIdx.x;  // 262144 threads
  int d  = tid & (kD - 1);
  int bc = tid >> 10;
  int b  = bc >> 5;
  int c  = bc & (kC - 1);

  float a[kN], q[kN];
  {
    const float* ap  = ws + kAOff + d;
    const float* cbp = ws + kCbOff + d;
    const float* sp  = ws + ((long)(b * kC + c) * kN) * kD + d;
#pragma unroll
    for (int n = 0; n < kN; ++n) {
      a[n] = ap[(long)n * kD];
      q[n] = cbp[(long)n * kD] * sp[(long)n * kD];  // cb_n * s_n
    }
  }
  float* yp = y + ((long)b * kLen + (long)c * kT) * kD + d;
#pragma unroll 1
  for (int t = 0; t < kT; ++t) {
#pragma unroll
    for (int n = 0; n < kN; ++n) q[n] *= a[n];  // q = cb * s * a^{t+1}
    float acc[8] = {0.f, 0.f, 0.f, 0.f, 0.f, 0.f, 0.f, 0.f};
#pragma unroll
    for (int n = 0; n < kN; ++n) acc[n & 7] += q[n];
    float s01 = acc[0] + acc[1], s23 = acc[2] + acc[3];
    float s45 = acc[4] + acc[5], s67 = acc[6] + acc[7];
    yp[(long)t * kD] += (s01 + s23) + (s45 + s67);
  }
}

extern "C" void kernel_launch(void* const* d_in, const int* in_sizes, int n_in,
                              void* d_out, int out_size, void* d_ws, size_t ws_size,
                              hipStream_t stream) {
  const float* x      = (const float*)d_in[0];
  const float* log_dt = (const float*)d_in[1];
  const float* Bm     = (const float*)d_in[2];
  const float* Cm     = (const float*)d_in[3];
  const float* Dv     = (const float*)d_in[4];
  float* y  = (float*)d_out;
  float* ws = (float*)d_ws;

  hipLaunchKernelGGL(s4d_coef_kernel, dim3((kN * kD) / 256), dim3(256), 0, stream,
                     log_dt, Bm, Cm, ws);
  hipLaunchKernelGGL(s4d_chunk_kernel, dim3((kBatch * kC * kD) / 256), dim3(256), 0, stream,
                     x, Dv, y, ws);
  hipLaunchKernelGGL(s4d_scan_kernel, dim3((kBatch * kN * kD) / 256), dim3(256), 0, stream,
                     ws);
  hipLaunchKernelGGL(s4d_corr_kernel, dim3((kBatch * kC * kD) / 256), dim3(256), 0, stream,
                     y, ws);
}

// Round 2
// 236.914 us; speedup vs baseline: 1.3532x; 1.3532x over previous
//
#include <hip/hip_runtime.h>
#include <math.h>

// S4D forward (conv mode) via chunked linear recurrence, loop order n-outer.
// y[b,l,d] = D[d]*x[b,l,d] + sum_n CB[d,n] * h_n[l],  h_n[l] = a_n h_n[l-1] + x[l]
// a = exp(dt*A), CB = C * expm1(dt*A)/A * B, A_n = -0.5*(n+1)
//
// P0 coef:  a[n][d], cb[n][d], a^T[n][d] tables (d fastest -> coalesced).
// P1 state: per (b,c,d): u_n = zero-init end state of chunk (Horner, n outer,
//           x[0..63] in regs).  4096 FMA/thread, ~80 VGPR.
// P2 scan:  s[c+1] = a^T s[c] + u[c] over 32 chunks (in-place; u -> s_start).
// P3 out:   h_n init = s_start, full recurrence + cb-dot + D-skip, y written
//           once.  8192 FMA/thread, x[64]+acc[64] in regs, ~145 VGPR.

namespace {
constexpr int kBatch = 8;
constexpr int kLen   = 2048;
constexpr int kD     = 1024;
constexpr int kN     = 64;         // states
constexpr int kT     = 64;         // chunk length
constexpr int kC     = kLen / kT;  // 32 chunks

constexpr long kUElems = (long)kBatch * kC * kN * kD;   // 16,777,216 floats
constexpr long kAOff   = kUElems;                        // a[n][d]
constexpr long kCbOff  = kAOff + (long)kN * kD;          // cb[n][d]
constexpr long kAtOff  = kCbOff + (long)kN * kD;         // a^T[n][d]
// total ws: (16777216 + 3*65536)*4 B = 67,895,296 B (~64.8 MiB)
}  // namespace

__global__ void s4d_coef_kernel(const float* __restrict__ log_dt,
                                const float* __restrict__ Bm,
                                const float* __restrict__ Cm,
                                float* __restrict__ ws) {
  int tid = blockIdx.x * blockDim.x + threadIdx.x;  // 65536 threads
  int d = tid & (kD - 1);
  int n = tid >> 10;
  float dt  = expf(log_dt[d]);
  float An  = -0.5f * (float)(n + 1);
  float dtA = dt * An;
  float a   = expf(dtA);
  float bbar = (expm1f(dtA) / An) * Bm[d * kN + n];
  float cb   = Cm[d * kN + n] * bbar;
  float aT   = expf(dtA * (float)kT);  // a^64
  ws[kAOff  + (long)n * kD + d] = a;
  ws[kCbOff + (long)n * kD + d] = cb;
  ws[kAtOff + (long)n * kD + d] = aT;
}

// Phase 1: chunk-local end states only (zero initial state).
__global__ __launch_bounds__(256) void s4d_state_kernel(
    const float* __restrict__ x, float* __restrict__ ws) {
  int tid = blockIdx.x * blockDim.x + threadIdx.x;  // 262144 threads
  int d  = tid & (kD - 1);   // consecutive lanes -> consecutive d: coalesced
  int bc = tid >> 10;
  int b  = bc >> 5;
  int c  = bc & (kC - 1);

  const float* xp = x + ((long)b * kLen + (long)c * kT) * kD + d;
  float xv[kT];
#pragma unroll
  for (int t = 0; t < kT; ++t) xv[t] = xp[(long)t * kD];

  const float* ap = ws + kAOff + d;
  float* up = ws + ((long)(b * kC + c) * kN) * kD + d;
#pragma unroll 4
  for (int n = 0; n < kN; ++n) {
    float a = ap[(long)n * kD];
    float h = 0.f;
#pragma unroll
    for (int t = 0; t < kT; ++t) h = fmaf(h, a, xv[t]);
    up[(long)n * kD] = h;
  }
}

// Phase 2: inter-chunk scan. After this, ws[u-region] holds s_start[c] =
// state at the END of chunk c-1 (i.e. initial state for chunk c).
__global__ void s4d_scan_kernel(float* __restrict__ ws) {
  int tid = blockIdx.x * blockDim.x + threadIdx.x;  // 524288 threads
  int d  = tid & (kD - 1);
  int bn = tid >> 10;
  int n  = bn & (kN - 1);
  int b  = bn >> 6;
  float aT = ws[kAtOff + (long)n * kD + d];
  float* up = ws + ((long)b * kC * kN + n) * kD + d;
  const long cstride = (long)kN * kD;
  float s = 0.f;
#pragma unroll 1
  for (int c = 0; c < kC; ++c) {
    float u = up[(long)c * cstride];
    up[(long)c * cstride] = s;  // in place: u[c] -> s_start[c]
    s = fmaf(aT, s, u);
  }
}

// Phase 3: full output. Recurrence with proper initial state, single y write.
__global__ __launch_bounds__(256, 2) void s4d_out_kernel(
    const float* __restrict__ x, const float* __restrict__ Dv,
    float* __restrict__ y, const float* __restrict__ ws) {
  int tid = blockIdx.x * blockDim.x + threadIdx.x;  // 262144 threads
  int d  = tid & (kD - 1);
  int bc = tid >> 10;
  int b  = bc >> 5;
  int c  = bc & (kC - 1);

  const float* xp = x + ((long)b * kLen + (long)c * kT) * kD + d;
  float xv[kT];
#pragma unroll
  for (int t = 0; t < kT; ++t) xv[t] = xp[(long)t * kD];

  float Dd = Dv[d];
  float acc[kT];
#pragma unroll
  for (int t = 0; t < kT; ++t) acc[t] = Dd * xv[t];

  const float* ap  = ws + kAOff + d;
  const float* cbp = ws + kCbOff + d;
  const float* sp  = ws + ((long)(b * kC + c) * kN) * kD + d;
#pragma unroll 2
  for (int n = 0; n < kN; ++n) {
    float a  = ap[(long)n * kD];
    float cb = cbp[(long)n * kD];
    float h  = sp[(long)n * kD];  // initial state for this chunk
#pragma unroll
    for (int t = 0; t < kT; ++t) {
      h = fmaf(h, a, xv[t]);
      acc[t] = fmaf(cb, h, acc[t]);
    }
  }

  float* yp = y + ((long)b * kLen + (long)c * kT) * kD + d;
#pragma unroll
  for (int t = 0; t < kT; ++t) yp[(long)t * kD] = acc[t];
}

extern "C" void kernel_launch(void* const* d_in, const int* in_sizes, int n_in,
                              void* d_out, int out_size, void* d_ws, size_t ws_size,
                              hipStream_t stream) {
  const float* x      = (const float*)d_in[0];
  const float* log_dt = (const float*)d_in[1];
  const float* Bm     = (const float*)d_in[2];
  const float* Cm     = (const float*)d_in[3];
  const float* Dv     = (const float*)d_in[4];
  float* y  = (float*)d_out;
  float* ws = (float*)d_ws;

  hipLaunchKernelGGL(s4d_coef_kernel, dim3((kN * kD) / 256), dim3(256), 0, stream,
                     log_dt, Bm, Cm, ws);
  hipLaunchKernelGGL(s4d_state_kernel, dim3((kBatch * kC * kD) / 256), dim3(256), 0, stream,
                     x, ws);
  hipLaunchKernelGGL(s4d_scan_kernel, dim3((kBatch * kN * kD) / 256), dim3(256), 0, stream,
                     ws);
  hipLaunchKernelGGL(s4d_out_kernel, dim3((kBatch * kC * kD) / 256), dim3(256), 0, stream,
                     x, Dv, y, ws);
}